// Round 8
// baseline (208.201 us; speedup 1.0000x reference)
//
#include <hip/hip_runtime.h>
#include <math.h>

#define PI_D 3.14159265358979323846
#define PI_F 3.14159265358979323846f

typedef _Float16 half8 __attribute__((ext_vector_type(8)));
typedef _Float16 half4v __attribute__((ext_vector_type(4)));
typedef float floatx4 __attribute__((ext_vector_type(4)));
#define MFMA16(a,b,c) __builtin_amdgcn_mfma_f32_16x16x32_f16(a,b,c,0,0,0)

// ---------------- scatter + small prep (wq, sgs, WS zero in block 0) ----------------
__global__ void k_scatter(const float* __restrict__ inp,
                          const float* __restrict__ p_scale,
                          const float* __restrict__ p_sigma,
                          const float* __restrict__ p_A,
                          const float* __restrict__ p_ic,
                          const float* __restrict__ Wg,
                          float* __restrict__ ft, float* __restrict__ wq,
                          float* __restrict__ sgs, float* __restrict__ WS) {
  int blk = blockIdx.x, t = threadIdx.x;
  if (blk == 0) {
    if (t < 32) {                                  // quadrature weights (fp64, bw=16)
      double jj = 2.0*(double)t + 1.0;
      double theta = PI_D * jj / 64.0;
      double s = 0.0;
      for (int k = 0; k < 16; ++k)
        s += sin(jj * (double)(2*k+1) * PI_D / 64.0) / (double)(2*k+1);
      wq[t] = (float)((2.0/16.0) * sin(theta) * s);
    } else if (t < 96) {                           // sgs[c] = sum_g Wg[c,g]
      int c = t - 32;
      float s = 0.f;
      for (int g = 0; g < 32; ++g) s += Wg[c*32 + g];
      sgs[c] = s;
    } else if (t < 224) {                          // zero WS (512 floats, float4)
      ((float4*)WS)[t - 96] = make_float4(0.f, 0.f, 0.f, 0.f);
    }
  }
  int i = blk * 256 + t;                           // 0 .. 262143
  float scale = p_scale[0];
  float sigma = p_sigma[0];
  float A     = p_A[0];
  float icomp = p_ic[0];
  int b = i >> 15;
  float x = inp[i*3+0];
  float y = inp[i*3+1];
  float z = inp[i*3+2];
  float r = sqrtf(x*x + y*y + z*z);
  r = fmaxf(r, 0.1f);
  float ctv = fminf(fmaxf(z / r, -1.0f), 1.0f);
  float theta = acosf(ctv);
  float phi = atan2f(y, x) + PI_F;
  float ct = theta * (32.0f / PI_F);
  float cp = phi * (32.0f / (2.0f * PI_F));
  float cr = r / scale * 8.0f;
  int it = (int)floorf(ct); it = min(max(it, 0), 31);
  int ip = (int)floorf(cp); ip = min(max(ip, 0), 31);
  int ir = (int)floorf(cr); ir = min(max(ir, 0), 7);
  float dt = ct - ((float)it + icomp);
  float dp = cp - ((float)ip + icomp);
  float dr = cr - ((float)ir + icomp);
  float d2 = dt*dt + dp*dp + dr*dr;
  float w = A * expf(-d2 / (2.0f * sigma * sigma));
  atomicAdd(&ft[((b*8 + ir)*32 + it)*32 + ip], w);
}

// ---------------- fused conv1+conv2+reduce + V/W2 fragment prep ----------------
// 256 blocks = b(8) * xt(32); also each block preps a disjoint 512-elem Vsw chunk
// (consumed only by the LATER k_head dispatch — no intra-kernel ordering needed).
__global__ __launch_bounds__(512) void k_conv12(
    const float* __restrict__ ft, const float* __restrict__ W1,
    const float* __restrict__ b1, const float* __restrict__ W2,
    const float* __restrict__ b2, const float* __restrict__ wq,
    const float* __restrict__ Wg, const float* __restrict__ Wc31,
    const float* __restrict__ Wc32,
    _Float16* __restrict__ VswH, _Float16* __restrict__ VswL,
    _Float16* __restrict__ W2swH, _Float16* __restrict__ W2swL,
    float* __restrict__ h2, float* __restrict__ WS) {
  __shared__ __align__(16) float ftt[8][5][32];    // [ic][xx][y]
  __shared__ __align__(16) float h1t[32][3][32];   // [ic2][xr][y]
  __shared__ __align__(16) float W1s[72*33];       // [rest][oc2], pad 33
  __shared__ __align__(16) float W2s[288*65];      // [rest][oc], pad 65
  int blk = blockIdx.x;
  int b = blk >> 5, xt = blk & 31;
  int t = threadIdx.x;                             // 512

  // ---- fragment prep (for k_head), disjoint chunks ----
  {
    int flat = blk * 512 + t;                      // 0 .. 131071
    int jj = flat & 7;
    int l  = (flat >> 3) & 63;
    int rest = flat >> 9;                          // mt*2 + ks
    int ks = rest & 1, mt = rest >> 1;
    int c = ks*32 + (l >> 4)*8 + jj;
    int m = mt*16 + (l & 15);                      // m = g*64 + d
    int g = m >> 6, d = m & 63;
    float val = Wg[c*32 + g] * Wc31[d*128 + c];
    _Float16 hi = (_Float16)val;
    VswH[flat] = hi;
    VswL[flat] = (_Float16)(val - (float)hi);
    if (flat < 2048) {                             // W2 A-frags (M-side = e)
      int ks2 = rest & 1, mt2 = rest >> 1;
      int e = mt2*16 + (l & 15);
      int dd = ks2*32 + (l >> 4)*8 + jj;
      float v2 = Wc32[e*64 + dd];
      _Float16 h2i = (_Float16)v2;
      W2swH[flat] = h2i;
      W2swL[flat] = (_Float16)(v2 - (float)h2i);
    }
  }

  // ---- coalesced weight staging w/ padded transpose ----
  for (int idx = t; idx < 2304; idx += 512) {      // W1: read flat (coalesced)
    int oc2 = idx / 72, rest = idx % 72;
    W1s[rest*33 + oc2] = W1[idx];
  }
  for (int idx = t; idx < 4608; idx += 512) {      // W2: float4 coalesced
    float4 v4 = ((const float4*)W2)[idx];
    int base = idx * 4;
    int oc = base / 288, r0 = base % 288;
    W2s[(r0+0)*65 + oc] = v4.x;
    W2s[(r0+1)*65 + oc] = v4.y;
    W2s[(r0+2)*65 + oc] = v4.z;
    W2s[(r0+3)*65 + oc] = v4.w;
  }
  for (int idx = t; idx < 1280; idx += 512) {
    int y = idx & 31, xx = (idx >> 5) % 5, ic = idx / 160;
    int xg = xt + xx - 2;
    ftt[ic][xx][y] = ((unsigned)xg < 32u) ? ft[b*8192 + ic*1024 + xg*32 + y] : 0.f;
  }
  __syncthreads();

  // ---- conv1: thread owns oc2 = grp*2+{0,1}, xr = 0..2, one y ----
  {
    int y = t & 31, grp = t >> 5;
    float acc[2][3];
    float bb0 = b1[grp*2+0], bb1 = b1[grp*2+1];
#pragma unroll
    for (int xr = 0; xr < 3; ++xr) { acc[0][xr] = bb0; acc[1][xr] = bb1; }
    for (int ic = 0; ic < 8; ++ic) {
      float v[5][3];
#pragma unroll
      for (int dyi = 0; dyi < 3; ++dyi) {
        int yy = y + dyi - 1;
        bool ok = ((unsigned)yy < 32u);
        int yc = min(max(yy, 0), 31);
#pragma unroll
        for (int xx = 0; xx < 5; ++xx) {
          float tv = ftt[ic][xx][yc];
          v[xx][dyi] = ok ? tv : 0.f;
        }
      }
#pragma unroll
      for (int k = 0; k < 9; ++k) {
        float w0 = W1s[(ic*9 + k)*33 + grp*2];
        float w1 = W1s[(ic*9 + k)*33 + grp*2 + 1];
        int dx = k / 3, dy = k % 3;
#pragma unroll
        for (int xr = 0; xr < 3; ++xr) {
          float vv = v[xr + dx][dy];
          acc[0][xr] = fmaf(vv, w0, acc[0][xr]);
          acc[1][xr] = fmaf(vv, w1, acc[1][xr]);
        }
      }
    }
#pragma unroll
    for (int xr = 0; xr < 3; ++xr) {
      int xg = xt + xr - 1;
      bool ok = ((unsigned)xg < 32u);
      h1t[grp*2+0][xr][y] = ok ? fmaxf(acc[0][xr], 0.f) : 0.f;
      h1t[grp*2+1][xr][y] = ok ? fmaxf(acc[1][xr], 0.f) : 0.f;
    }
  }
  __syncthreads();

  // ---- conv2 + store + reduce: thread owns oc = og*4..+3, one y ----
  {
    int y = t & 31, og = t >> 5, oc0 = og*4;
    float a0 = b2[oc0+0], a1 = b2[oc0+1], a2 = b2[oc0+2], a3 = b2[oc0+3];
    for (int ic2 = 0; ic2 < 32; ++ic2) {
      float v[3][3];
#pragma unroll
      for (int dyi = 0; dyi < 3; ++dyi) {
        int yy = y + dyi - 1;
        bool ok = ((unsigned)yy < 32u);
        int yc = min(max(yy, 0), 31);
#pragma unroll
        for (int xxi = 0; xxi < 3; ++xxi) {
          float tv = h1t[ic2][xxi][yc];
          v[xxi][dyi] = ok ? tv : 0.f;
        }
      }
#pragma unroll
      for (int k = 0; k < 9; ++k) {
        int row = (ic2*9 + k)*65 + oc0;
        float w0 = W2s[row+0], w1 = W2s[row+1], w2 = W2s[row+2], w3 = W2s[row+3];
        float vv = v[k/3][k%3];
        a0 = fmaf(vv, w0, a0);
        a1 = fmaf(vv, w1, a1);
        a2 = fmaf(vv, w2, a2);
        a3 = fmaf(vv, w3, a3);
      }
    }
    float r0 = fmaxf(a0, 0.f), r1 = fmaxf(a1, 0.f);
    float r2 = fmaxf(a2, 0.f), r3 = fmaxf(a3, 0.f);
    int pp = xt*32 + y;
    h2[(b*64 + oc0+0)*1024 + pp] = r0;
    h2[(b*64 + oc0+1)*1024 + pp] = r1;
    h2[(b*64 + oc0+2)*1024 + pp] = r2;
    h2[(b*64 + oc0+3)*1024 + pp] = r3;
    float wqv = wq[y];
    float s0 = r0*wqv, s1 = r1*wqv, s2 = r2*wqv, s3 = r3*wqv;
#pragma unroll
    for (int m = 1; m < 32; m <<= 1) {
      s0 += __shfl_xor(s0, m, 64);
      s1 += __shfl_xor(s1, m, 64);
      s2 += __shfl_xor(s2, m, 64);
      s3 += __shfl_xor(s3, m, 64);
    }
    if ((t & 31) == 0) {
      atomicAdd(&WS[b*64 + oc0+0], s0);
      atomicAdd(&WS[b*64 + oc0+1], s1);
      atomicAdd(&WS[b*64 + oc0+2], s2);
      atomicAdd(&WS[b*64 + oc0+3], s3);
    }
  }
}

// ---------------- head (MFMA): 1024 blocks = b(8)*x(32)*h(2)*yh(2) ----------------
// y-split: each block computes 16 y -> h3H 36 KB -> 4 blocks/CU
__global__ __launch_bounds__(512, 8) void k_head(
    const float* __restrict__ h2, const float* __restrict__ WS,
    const float* __restrict__ sgs,
    const float* __restrict__ Wc31, const float* __restrict__ bc31,
    const float* __restrict__ bc32,
    const half8* __restrict__ VswH, const half8* __restrict__ VswL,
    const half8* __restrict__ W2swH, const half8* __restrict__ W2swL,
    float* __restrict__ out, float* __restrict__ blockmax) {
  __shared__ __align__(16) _Float16 h3H[256*72];   // [rowc=y_l*16+gl][d sw], 36 KiB
  __shared__ float Ks[64];
  __shared__ float vbuf2[128];
  int blk = blockIdx.x;            // 1024
  int b = blk >> 7, x = (blk >> 2) & 31, h = (blk >> 1) & 1, yh = blk & 1;
  int t = threadIdx.x;             // 512 = 8 waves
  int lane = t & 63, w = t >> 6;
  int n16 = lane & 15, quad = lane >> 4;

  if (t < 64) {
    float acc = bc31[t];
    const float* wr = Wc31 + t*128 + 64;
    const float* wsb = WS + b*64;
    for (int c = 0; c < 64; ++c)
      acc = fmaf(wr[c], sgs[c]*wsb[c], acc);
    Ks[t] = acc;
  }

  // GEMM1 B-frags (h2) for this y-half, split f16
  half8 bh0, bh1, bl0, bl1;
  {
    const float* h2b = h2 + (size_t)b*64*1024 + x*32 + yh*16;
#pragma unroll
    for (int j = 0; j < 8; ++j) {
      int c0 = quad*8 + j;         // ks=0
      float f0 = h2b[c0*1024 + n16];
      float f1 = h2b[(32 + c0)*1024 + n16];
      _Float16 g0 = (_Float16)f0, g1 = (_Float16)f1;
      bh0[j] = g0;  bl0[j] = (_Float16)(f0 - (float)g0);
      bh1[j] = g1;  bl1[j] = (_Float16)(f1 - (float)g1);
    }
  }
  int mt2 = w & 1;
  half8 a2h0 = W2swH[(mt2*2 + 0)*64 + lane];
  half8 a2h1 = W2swH[(mt2*2 + 1)*64 + lane];
  half8 a2l0 = W2swL[(mt2*2 + 0)*64 + lane];
  half8 a2l1 = W2swL[(mt2*2 + 1)*64 + lane];
  float bias_e[4];
#pragma unroll
  for (int r = 0; r < 4; ++r) bias_e[r] = bc32[mt2*16 + quad*4 + r];
  __syncthreads();                 // Ks ready

  // ---- phase A: GEMM1, wave owns mt = h*64 + w*8 + i, N=16 (this y-half) ----
  for (int i = 0; i < 8; ++i) {
    int mt = h*64 + w*8 + i;
    half8 ah0 = VswH[(mt*2 + 0)*64 + lane];
    half8 ah1 = VswH[(mt*2 + 1)*64 + lane];
    half8 al0 = VswL[(mt*2 + 0)*64 + lane];
    half8 al1 = VswL[(mt*2 + 1)*64 + lane];
    floatx4 acc = {0.f, 0.f, 0.f, 0.f};
    acc = MFMA16(ah0, bh0, acc);
    acc = MFMA16(ah0, bl0, acc);
    acc = MFMA16(al0, bh0, acc);
    acc = MFMA16(ah1, bh1, acc);
    acc = MFMA16(ah1, bl1, acc);
    acc = MFMA16(al1, bh1, acc);
    int g = mt >> 2, gl = g & 15;
    int dbase = (mt & 3)*16 + quad*4;
    float4 kv = *(const float4*)&Ks[dbase];
    int y_l = n16;                 // local y = C col
    int rowc = y_l*16 + gl;
    int dsw = (dbase + y_l*8) & 63;
    half4v hv;
    hv[0] = (_Float16)fmaxf(acc[0] + kv.x, 0.f);
    hv[1] = (_Float16)fmaxf(acc[1] + kv.y, 0.f);
    hv[2] = (_Float16)fmaxf(acc[2] + kv.z, 0.f);
    hv[3] = (_Float16)fmaxf(acc[3] + kv.w, 0.f);
    *(half4v*)&h3H[rowc*72 + dsw] = hv;
  }
  __syncthreads();
  // ---- phase B: GEMM2, wave group (w>>1) owns y_l = grp*4+i, e-tile mt2 ----
  float vmax[4] = {-3.4e38f, -3.4e38f, -3.4e38f, -3.4e38f};
  int grp = w >> 1;
  for (int i = 0; i < 4; ++i) {
    int y_l = grp*4 + i;
    int rowc = y_l*16 + n16;       // gl = n16
    int dsw0 = (quad*8 + y_l*8) & 63;
    int dsw1 = (32 + quad*8 + y_l*8) & 63;
    half8 b2h0 = *(const half8*)&h3H[rowc*72 + dsw0];
    half8 b2h1 = *(const half8*)&h3H[rowc*72 + dsw1];
    floatx4 acc = {0.f, 0.f, 0.f, 0.f};
    acc = MFMA16(a2h0, b2h0, acc);
    acc = MFMA16(a2l0, b2h0, acc);
    acc = MFMA16(a2h1, b2h1, acc);
    acc = MFMA16(a2l1, b2h1, acc);
    int y = yh*16 + y_l, g = h*16 + n16;
    size_t base = (((size_t)(b*32 + mt2*16 + quad*4))*1024 + (size_t)(x*32 + y))*32 + g;
#pragma unroll
    for (int r = 0; r < 4; ++r) {
      float v = acc[r] + bias_e[r];
      out[base + (size_t)r*32768] = v;
      vmax[r] = fmaxf(vmax[r], v);
    }
  }
  // block max over e
#pragma unroll
  for (int m = 1; m < 16; m <<= 1) {
#pragma unroll
    for (int r = 0; r < 4; ++r)
      vmax[r] = fmaxf(vmax[r], __shfl_xor(vmax[r], m, 64));
  }
  if (n16 == 0) {
#pragma unroll
    for (int r = 0; r < 4; ++r) vbuf2[w*16 + quad*4 + r] = vmax[r];
  }
  __syncthreads();
  if (t < 32) {
    int e = t, m2 = e >> 4, el = e & 15;
    float mm = fmaxf(fmaxf(vbuf2[(m2+0)*16 + el], vbuf2[(m2+2)*16 + el]),
                     fmaxf(vbuf2[(m2+4)*16 + el], vbuf2[(m2+6)*16 + el]));
    blockmax[blk*32 + e] = mm;
  }
}

// ---------------- finalize: ft_g[b,e] = max over 128 sub-blocks (x,h,yh) ----------------
__global__ void k_final(const float* __restrict__ blockmax, float* __restrict__ ftg) {
  int t = threadIdx.x;             // 256 = b(8)*e(32)
  int b = t >> 5, e = t & 31;
  float m = -3.4e38f;
  for (int s = 0; s < 128; ++s) m = fmaxf(m, blockmax[(b*128 + s)*32 + e]);
  ftg[b*32 + e] = m;
}

extern "C" void kernel_launch(void* const* d_in, const int* in_sizes, int n_in,
                              void* d_out, int out_size, void* d_ws, size_t ws_size,
                              hipStream_t stream) {
  const float* inputs = (const float*)d_in[0];
  const float* scale  = (const float*)d_in[1];
  const float* sigma  = (const float*)d_in[2];
  const float* A      = (const float*)d_in[3];
  const float* icmp   = (const float*)d_in[4];
  // d_in[5]=res_pt(32), d_in[6]=res_r(8) — compile-time constants here
  const float* W1   = (const float*)d_in[7];
  const float* b1   = (const float*)d_in[8];
  const float* W2   = (const float*)d_in[9];
  const float* b2   = (const float*)d_in[10];
  const float* Wg   = (const float*)d_in[11];
  const float* Wc31 = (const float*)d_in[12];
  const float* bc31 = (const float*)d_in[13];
  const float* Wc32 = (const float*)d_in[14];
  const float* bc32 = (const float*)d_in[15];

  float* ws    = (float*)d_ws;
  float* ft    = ws;               // 65536
  float* h2    = ws + 327680;      // 524288
  float* WS    = ws + 851968;      // 512
  float* bmax  = ws + 852480;      // 32768
  float* wq    = ws + 885248;      // 32
  float* sgs   = ws + 885280;      // 64
  _Float16* VswH  = (_Float16*)(ws + 885344);   // 131072 f16
  _Float16* VswL  = (_Float16*)(ws + 950880);   // 131072 f16
  _Float16* W2swH = (_Float16*)(ws + 1016416);  // 2048 f16
  _Float16* W2swL = (_Float16*)(ws + 1017440);  // 2048 f16
  float* out   = (float*)d_out;    // 8388608
  float* ftg   = out + 8388608;    // 256

  hipMemsetAsync(ft, 0, 65536*sizeof(float), stream);
  k_scatter<<<1024, 256, 0, stream>>>(inputs, scale, sigma, A, icmp, Wg,
                                      ft, wq, sgs, WS);
  k_conv12<<<256, 512, 0, stream>>>(ft, W1, b1, W2, b2, wq, Wg, Wc31, Wc32,
                                    VswH, VswL, W2swH, W2swL, h2, WS);
  k_head<<<1024, 512, 0, stream>>>(h2, WS, sgs, Wc31, bc31, bc32,
                                   (const half8*)VswH, (const half8*)VswL,
                                   (const half8*)W2swH, (const half8*)W2swL,
                                   out, bmax);
  k_final<<<1, 256, 0, stream>>>(bmax, ftg);
}

// Round 9
// 164.261 us; speedup vs baseline: 1.2675x; 1.2675x over previous
//
#include <hip/hip_runtime.h>
#include <math.h>

#define PI_D 3.14159265358979323846
#define PI_F 3.14159265358979323846f

typedef _Float16 half8 __attribute__((ext_vector_type(8)));
typedef _Float16 half4v __attribute__((ext_vector_type(4)));
typedef float floatx4 __attribute__((ext_vector_type(4)));
#define MFMA16(a,b,c) __builtin_amdgcn_mfma_f32_16x16x32_f16(a,b,c,0,0,0)

// ---------------- scatter + small prep (wq, sgs, WS zero in block 0) ----------------
__global__ void k_scatter(const float* __restrict__ inp,
                          const float* __restrict__ p_scale,
                          const float* __restrict__ p_sigma,
                          const float* __restrict__ p_A,
                          const float* __restrict__ p_ic,
                          const float* __restrict__ Wg,
                          float* __restrict__ ft, float* __restrict__ wq,
                          float* __restrict__ sgs, float* __restrict__ WS) {
  int blk = blockIdx.x, t = threadIdx.x;
  if (blk == 0) {
    if (t < 32) {                                  // quadrature weights (fp64, bw=16)
      double jj = 2.0*(double)t + 1.0;
      double theta = PI_D * jj / 64.0;
      double s = 0.0;
      for (int k = 0; k < 16; ++k)
        s += sin(jj * (double)(2*k+1) * PI_D / 64.0) / (double)(2*k+1);
      wq[t] = (float)((2.0/16.0) * sin(theta) * s);
    } else if (t < 96) {                           // sgs[c] = sum_g Wg[c,g]
      int c = t - 32;
      float s = 0.f;
      for (int g = 0; g < 32; ++g) s += Wg[c*32 + g];
      sgs[c] = s;
    } else if (t < 224) {                          // zero WS (512 floats, float4)
      ((float4*)WS)[t - 96] = make_float4(0.f, 0.f, 0.f, 0.f);
    }
  }
  int i = blk * 256 + t;                           // 0 .. 262143
  float scale = p_scale[0];
  float sigma = p_sigma[0];
  float A     = p_A[0];
  float icomp = p_ic[0];
  int b = i >> 15;
  float x = inp[i*3+0];
  float y = inp[i*3+1];
  float z = inp[i*3+2];
  float r = sqrtf(x*x + y*y + z*z);
  r = fmaxf(r, 0.1f);
  float ctv = fminf(fmaxf(z / r, -1.0f), 1.0f);
  float theta = acosf(ctv);
  float phi = atan2f(y, x) + PI_F;
  float ct = theta * (32.0f / PI_F);
  float cp = phi * (32.0f / (2.0f * PI_F));
  float cr = r / scale * 8.0f;
  int it = (int)floorf(ct); it = min(max(it, 0), 31);
  int ip = (int)floorf(cp); ip = min(max(ip, 0), 31);
  int ir = (int)floorf(cr); ir = min(max(ir, 0), 7);
  float dt = ct - ((float)it + icomp);
  float dp = cp - ((float)ip + icomp);
  float dr = cr - ((float)ir + icomp);
  float d2 = dt*dt + dp*dp + dr*dr;
  float w = A * expf(-d2 / (2.0f * sigma * sigma));
  atomicAdd(&ft[((b*8 + ir)*32 + it)*32 + ip], w);
}

// ---------------- fused conv1+conv2+reduce + V/W2 fragment prep ----------------
__global__ __launch_bounds__(512) void k_conv12(
    const float* __restrict__ ft, const float* __restrict__ W1,
    const float* __restrict__ b1, const float* __restrict__ W2,
    const float* __restrict__ b2, const float* __restrict__ wq,
    const float* __restrict__ Wg, const float* __restrict__ Wc31,
    const float* __restrict__ Wc32,
    _Float16* __restrict__ VswH, _Float16* __restrict__ VswL,
    _Float16* __restrict__ W2swH, _Float16* __restrict__ W2swL,
    float* __restrict__ h2, float* __restrict__ WS) {
  __shared__ __align__(16) float ftt[8][5][32];    // [ic][xx][y]
  __shared__ __align__(16) float h1t[32][3][32];   // [ic2][xr][y]
  __shared__ __align__(16) float W1s[72*33];       // [rest][oc2], pad 33
  __shared__ __align__(16) float W2s[288*65];      // [rest][oc], pad 65
  int blk = blockIdx.x;
  int b = blk >> 5, xt = blk & 31;
  int t = threadIdx.x;                             // 512

  // ---- fragment prep (for k_head), disjoint chunks ----
  {
    int flat = blk * 512 + t;                      // 0 .. 131071
    int jj = flat & 7;
    int l  = (flat >> 3) & 63;
    int rest = flat >> 9;                          // mt*2 + ks
    int ks = rest & 1, mt = rest >> 1;
    int c = ks*32 + (l >> 4)*8 + jj;
    int m = mt*16 + (l & 15);                      // m = g*64 + d
    int g = m >> 6, d = m & 63;
    float val = Wg[c*32 + g] * Wc31[d*128 + c];
    _Float16 hi = (_Float16)val;
    VswH[flat] = hi;
    VswL[flat] = (_Float16)(val - (float)hi);
    if (flat < 2048) {                             // W2 A-frags (M-side = e)
      int ks2 = rest & 1, mt2 = rest >> 1;
      int e = mt2*16 + (l & 15);
      int dd = ks2*32 + (l >> 4)*8 + jj;
      float v2 = Wc32[e*64 + dd];
      _Float16 h2i = (_Float16)v2;
      W2swH[flat] = h2i;
      W2swL[flat] = (_Float16)(v2 - (float)h2i);
    }
  }

  // ---- coalesced weight staging w/ padded transpose ----
  for (int idx = t; idx < 2304; idx += 512) {      // W1: read flat (coalesced)
    int oc2 = idx / 72, rest = idx % 72;
    W1s[rest*33 + oc2] = W1[idx];
  }
  for (int idx = t; idx < 4608; idx += 512) {      // W2: float4 coalesced
    float4 v4 = ((const float4*)W2)[idx];
    int base = idx * 4;
    int oc = base / 288, r0 = base % 288;
    W2s[(r0+0)*65 + oc] = v4.x;
    W2s[(r0+1)*65 + oc] = v4.y;
    W2s[(r0+2)*65 + oc] = v4.z;
    W2s[(r0+3)*65 + oc] = v4.w;
  }
  for (int idx = t; idx < 1280; idx += 512) {
    int y = idx & 31, xx = (idx >> 5) % 5, ic = idx / 160;
    int xg = xt + xx - 2;
    ftt[ic][xx][y] = ((unsigned)xg < 32u) ? ft[b*8192 + ic*1024 + xg*32 + y] : 0.f;
  }
  __syncthreads();

  // ---- conv1: thread owns oc2 = grp*2+{0,1}, xr = 0..2, one y ----
  {
    int y = t & 31, grp = t >> 5;
    float acc[2][3];
    float bb0 = b1[grp*2+0], bb1 = b1[grp*2+1];
#pragma unroll
    for (int xr = 0; xr < 3; ++xr) { acc[0][xr] = bb0; acc[1][xr] = bb1; }
    for (int ic = 0; ic < 8; ++ic) {
      float v[5][3];
#pragma unroll
      for (int dyi = 0; dyi < 3; ++dyi) {
        int yy = y + dyi - 1;
        bool ok = ((unsigned)yy < 32u);
        int yc = min(max(yy, 0), 31);
#pragma unroll
        for (int xx = 0; xx < 5; ++xx) {
          float tv = ftt[ic][xx][yc];
          v[xx][dyi] = ok ? tv : 0.f;
        }
      }
#pragma unroll
      for (int k = 0; k < 9; ++k) {
        float w0 = W1s[(ic*9 + k)*33 + grp*2];
        float w1 = W1s[(ic*9 + k)*33 + grp*2 + 1];
        int dx = k / 3, dy = k % 3;
#pragma unroll
        for (int xr = 0; xr < 3; ++xr) {
          float vv = v[xr + dx][dy];
          acc[0][xr] = fmaf(vv, w0, acc[0][xr]);
          acc[1][xr] = fmaf(vv, w1, acc[1][xr]);
        }
      }
    }
#pragma unroll
    for (int xr = 0; xr < 3; ++xr) {
      int xg = xt + xr - 1;
      bool ok = ((unsigned)xg < 32u);
      h1t[grp*2+0][xr][y] = ok ? fmaxf(acc[0][xr], 0.f) : 0.f;
      h1t[grp*2+1][xr][y] = ok ? fmaxf(acc[1][xr], 0.f) : 0.f;
    }
  }
  __syncthreads();

  // ---- conv2 + store + reduce: thread owns oc = og*4..+3, one y ----
  {
    int y = t & 31, og = t >> 5, oc0 = og*4;
    float a0 = b2[oc0+0], a1 = b2[oc0+1], a2 = b2[oc0+2], a3 = b2[oc0+3];
    for (int ic2 = 0; ic2 < 32; ++ic2) {
      float v[3][3];
#pragma unroll
      for (int dyi = 0; dyi < 3; ++dyi) {
        int yy = y + dyi - 1;
        bool ok = ((unsigned)yy < 32u);
        int yc = min(max(yy, 0), 31);
#pragma unroll
        for (int xxi = 0; xxi < 3; ++xxi) {
          float tv = h1t[ic2][xxi][yc];
          v[xxi][dyi] = ok ? tv : 0.f;
        }
      }
#pragma unroll
      for (int k = 0; k < 9; ++k) {
        int row = (ic2*9 + k)*65 + oc0;
        float w0 = W2s[row+0], w1 = W2s[row+1], w2 = W2s[row+2], w3 = W2s[row+3];
        float vv = v[k/3][k%3];
        a0 = fmaf(vv, w0, a0);
        a1 = fmaf(vv, w1, a1);
        a2 = fmaf(vv, w2, a2);
        a3 = fmaf(vv, w3, a3);
      }
    }
    float r0 = fmaxf(a0, 0.f), r1 = fmaxf(a1, 0.f);
    float r2 = fmaxf(a2, 0.f), r3 = fmaxf(a3, 0.f);
    int pp = xt*32 + y;
    h2[(b*64 + oc0+0)*1024 + pp] = r0;
    h2[(b*64 + oc0+1)*1024 + pp] = r1;
    h2[(b*64 + oc0+2)*1024 + pp] = r2;
    h2[(b*64 + oc0+3)*1024 + pp] = r3;
    float wqv = wq[y];
    float s0 = r0*wqv, s1 = r1*wqv, s2 = r2*wqv, s3 = r3*wqv;
#pragma unroll
    for (int m = 1; m < 32; m <<= 1) {
      s0 += __shfl_xor(s0, m, 64);
      s1 += __shfl_xor(s1, m, 64);
      s2 += __shfl_xor(s2, m, 64);
      s3 += __shfl_xor(s3, m, 64);
    }
    if ((t & 31) == 0) {
      atomicAdd(&WS[b*64 + oc0+0], s0);
      atomicAdd(&WS[b*64 + oc0+1], s1);
      atomicAdd(&WS[b*64 + oc0+2], s2);
      atomicAdd(&WS[b*64 + oc0+3], s3);
    }
  }
}

// ---------------- head (MFMA): grid 512 = b(8)*x(32)*h(2), h = g-half (R7 version) ----
__global__ __launch_bounds__(512, 4) void k_head(
    const float* __restrict__ h2, const float* __restrict__ WS,
    const float* __restrict__ sgs,
    const float* __restrict__ Wc31, const float* __restrict__ bc31,
    const float* __restrict__ bc32,
    const half8* __restrict__ VswH, const half8* __restrict__ VswL,
    const half8* __restrict__ W2swH, const half8* __restrict__ W2swL,
    float* __restrict__ out, float* __restrict__ blockmax) {
  __shared__ __align__(16) _Float16 h3H[512*72];   // [rowc=y*16+gl][d sw], 72 KiB
  __shared__ float Ks[64];
  __shared__ float vbuf2[128];
  int blk = blockIdx.x;            // 512
  int b = blk >> 6, x = (blk >> 1) & 31, h = blk & 1;
  int t = threadIdx.x;             // 512 = 8 waves
  int lane = t & 63, w = t >> 6;
  int n16 = lane & 15, quad = lane >> 4;

  if (t < 64) {
    float acc = bc31[t];
    const float* wr = Wc31 + t*128 + 64;
    const float* wsb = WS + b*64;
    for (int c = 0; c < 64; ++c)
      acc = fmaf(wr[c], sgs[c]*wsb[c], acc);
    Ks[t] = acc;
  }

  // GEMM1 B-frags (h2) loaded directly from global, split f16
  half8 bh00, bh01, bh10, bh11, bl00, bl01, bl10, bl11;
  {
    const float* h2b = h2 + (size_t)b*64*1024 + x*32;
#pragma unroll
    for (int j = 0; j < 8; ++j) {
      int c0 = quad*8 + j;         // ks=0
      int c1 = 32 + c0;            // ks=1
      float f00 = h2b[c0*1024 + n16];
      float f01 = h2b[c1*1024 + n16];
      float f10 = h2b[c0*1024 + 16 + n16];
      float f11 = h2b[c1*1024 + 16 + n16];
      _Float16 g00 = (_Float16)f00, g01 = (_Float16)f01;
      _Float16 g10 = (_Float16)f10, g11 = (_Float16)f11;
      bh00[j] = g00;  bl00[j] = (_Float16)(f00 - (float)g00);
      bh01[j] = g01;  bl01[j] = (_Float16)(f01 - (float)g01);
      bh10[j] = g10;  bl10[j] = (_Float16)(f10 - (float)g10);
      bh11[j] = g11;  bl11[j] = (_Float16)(f11 - (float)g11);
    }
  }
  int mt2 = w & 1;
  half8 a2h0 = W2swH[(mt2*2 + 0)*64 + lane];
  half8 a2h1 = W2swH[(mt2*2 + 1)*64 + lane];
  half8 a2l0 = W2swL[(mt2*2 + 0)*64 + lane];
  half8 a2l1 = W2swL[(mt2*2 + 1)*64 + lane];
  float bias_e[4];
#pragma unroll
  for (int r = 0; r < 4; ++r) bias_e[r] = bc32[mt2*16 + quad*4 + r];
  __syncthreads();                 // Ks ready

  // ---- phase A: GEMM1, wave owns mt = h*64 + w*8 + i ----
  for (int i = 0; i < 8; ++i) {
    int mt = h*64 + w*8 + i;
    half8 ah0 = VswH[(mt*2 + 0)*64 + lane];
    half8 ah1 = VswH[(mt*2 + 1)*64 + lane];
    half8 al0 = VswL[(mt*2 + 0)*64 + lane];
    half8 al1 = VswL[(mt*2 + 1)*64 + lane];
    floatx4 acc0 = {0.f, 0.f, 0.f, 0.f};
    floatx4 acc1 = {0.f, 0.f, 0.f, 0.f};
    acc0 = MFMA16(ah0, bh00, acc0);  acc1 = MFMA16(ah0, bh10, acc1);
    acc0 = MFMA16(ah0, bl00, acc0);  acc1 = MFMA16(ah0, bl10, acc1);
    acc0 = MFMA16(al0, bh00, acc0);  acc1 = MFMA16(al0, bh10, acc1);
    acc0 = MFMA16(ah1, bh01, acc0);  acc1 = MFMA16(ah1, bh11, acc1);
    acc0 = MFMA16(ah1, bl01, acc0);  acc1 = MFMA16(ah1, bl11, acc1);
    acc0 = MFMA16(al1, bh01, acc0);  acc1 = MFMA16(al1, bh11, acc1);
    int g = mt >> 2, gl = g & 15;
    int dbase = (mt & 3)*16 + quad*4;
    float4 kv = *(const float4*)&Ks[dbase];
#pragma unroll
    for (int nt = 0; nt < 2; ++nt) {
      floatx4 a = nt ? acc1 : acc0;
      int y = nt*16 + n16;
      int rowc = y*16 + gl;
      int dsw = (dbase + y*8) & 63;
      half4v hv;
      hv[0] = (_Float16)fmaxf(a[0] + kv.x, 0.f);
      hv[1] = (_Float16)fmaxf(a[1] + kv.y, 0.f);
      hv[2] = (_Float16)fmaxf(a[2] + kv.z, 0.f);
      hv[3] = (_Float16)fmaxf(a[3] + kv.w, 0.f);
      *(half4v*)&h3H[rowc*72 + dsw] = hv;
    }
  }
  __syncthreads();
  // ---- phase B: GEMM2, wave owns nt2 = (w>>1)*8 + i (= y), e-tile mt2 ----
  float vmax[4] = {-3.4e38f, -3.4e38f, -3.4e38f, -3.4e38f};
  for (int i = 0; i < 8; ++i) {
    int nt2 = (w >> 1)*8 + i;
    int rowc = nt2*16 + n16;       // gl = n16
    int dsw0 = (quad*8 + nt2*8) & 63;
    int dsw1 = (32 + quad*8 + nt2*8) & 63;
    half8 b2h0 = *(const half8*)&h3H[rowc*72 + dsw0];
    half8 b2h1 = *(const half8*)&h3H[rowc*72 + dsw1];
    floatx4 acc = {0.f, 0.f, 0.f, 0.f};
    acc = MFMA16(a2h0, b2h0, acc);
    acc = MFMA16(a2l0, b2h0, acc);
    acc = MFMA16(a2h1, b2h1, acc);
    acc = MFMA16(a2l1, b2h1, acc);
    int y = nt2, g = h*16 + n16;
    size_t base = (((size_t)(b*32 + mt2*16 + quad*4))*1024 + (size_t)(x*32 + y))*32 + g;
#pragma unroll
    for (int r = 0; r < 4; ++r) {
      float v = acc[r] + bias_e[r];
      out[base + (size_t)r*32768] = v;
      vmax[r] = fmaxf(vmax[r], v);
    }
  }
  // block max over e
#pragma unroll
  for (int m = 1; m < 16; m <<= 1) {
#pragma unroll
    for (int r = 0; r < 4; ++r)
      vmax[r] = fmaxf(vmax[r], __shfl_xor(vmax[r], m, 64));
  }
  if (n16 == 0) {
#pragma unroll
    for (int r = 0; r < 4; ++r) vbuf2[w*16 + quad*4 + r] = vmax[r];
  }
  __syncthreads();
  if (t < 32) {
    int e = t, m2 = e >> 4, el = e & 15;
    float mm = fmaxf(fmaxf(vbuf2[(m2+0)*16 + el], vbuf2[(m2+2)*16 + el]),
                     fmaxf(vbuf2[(m2+4)*16 + el], vbuf2[(m2+6)*16 + el]));
    blockmax[blk*32 + e] = mm;
  }
}

// ---------------- finalize: ft_g[b,e] = max over 64 sub-blocks (x,h) ----------------
__global__ void k_final(const float* __restrict__ blockmax, float* __restrict__ ftg) {
  int t = threadIdx.x;             // 256 = b(8)*e(32)
  int b = t >> 5, e = t & 31;
  float m = -3.4e38f;
  for (int s = 0; s < 64; ++s) m = fmaxf(m, blockmax[(b*64 + s)*32 + e]);
  ftg[b*32 + e] = m;
}

extern "C" void kernel_launch(void* const* d_in, const int* in_sizes, int n_in,
                              void* d_out, int out_size, void* d_ws, size_t ws_size,
                              hipStream_t stream) {
  const float* inputs = (const float*)d_in[0];
  const float* scale  = (const float*)d_in[1];
  const float* sigma  = (const float*)d_in[2];
  const float* A      = (const float*)d_in[3];
  const float* icmp   = (const float*)d_in[4];
  // d_in[5]=res_pt(32), d_in[6]=res_r(8) — compile-time constants here
  const float* W1   = (const float*)d_in[7];
  const float* b1   = (const float*)d_in[8];
  const float* W2   = (const float*)d_in[9];
  const float* b2   = (const float*)d_in[10];
  const float* Wg   = (const float*)d_in[11];
  const float* Wc31 = (const float*)d_in[12];
  const float* bc31 = (const float*)d_in[13];
  const float* Wc32 = (const float*)d_in[14];
  const float* bc32 = (const float*)d_in[15];

  float* ws    = (float*)d_ws;
  float* ft    = ws;               // 65536
  float* h2    = ws + 327680;      // 524288
  float* WS    = ws + 851968;      // 512
  float* bmax  = ws + 852480;      // 16384
  float* wq    = ws + 885248;      // 32
  float* sgs   = ws + 885280;      // 64
  _Float16* VswH  = (_Float16*)(ws + 885344);   // 131072 f16
  _Float16* VswL  = (_Float16*)(ws + 950880);   // 131072 f16
  _Float16* W2swH = (_Float16*)(ws + 1016416);  // 2048 f16
  _Float16* W2swL = (_Float16*)(ws + 1017440);  // 2048 f16
  float* out   = (float*)d_out;    // 8388608
  float* ftg   = out + 8388608;    // 256

  hipMemsetAsync(ft, 0, 65536*sizeof(float), stream);
  k_scatter<<<1024, 256, 0, stream>>>(inputs, scale, sigma, A, icmp, Wg,
                                      ft, wq, sgs, WS);
  k_conv12<<<256, 512, 0, stream>>>(ft, W1, b1, W2, b2, wq, Wg, Wc31, Wc32,
                                    VswH, VswL, W2swH, W2swL, h2, WS);
  k_head<<<512, 512, 0, stream>>>(h2, WS, sgs, Wc31, bc31, bc32,
                                  (const half8*)VswH, (const half8*)VswL,
                                  (const half8*)W2swH, (const half8*)W2swL,
                                  out, bmax);
  k_final<<<1, 256, 0, stream>>>(bmax, ftg);
}